// Round 1
// 1358.233 us; speedup vs baseline: 1.1256x; 1.1256x over previous
//
#include <hip/hip_runtime.h>

#define B_  4
#define S_  1024
#define H_  32
#define D_  128
#define E_  4096
#define T_  4096
#define NB_ 64
#define BS_ 16
#define NT_ 128   // K-tiles of 32 over K=4096

typedef __attribute__((ext_vector_type(8))) __bf16 bf16x8;
typedef __attribute__((ext_vector_type(4))) __bf16 bf16x4;
typedef __attribute__((ext_vector_type(4))) float f32x4;

__device__ __forceinline__ void gload_lds16(const __bf16* g, __bf16* l) {
  __builtin_amdgcn_global_load_lds((const __attribute__((address_space(1))) void*)g,
                                   (__attribute__((address_space(3))) void*)l, 16, 0, 0);
}

// ---------------------------------------------------------------- converts
__global__ __launch_bounds__(256) void k_convert_hs(const float* __restrict__ x,
                                                    __bf16* __restrict__ y, int n4) {
  int i = blockIdx.x * 256 + threadIdx.x;
  if (i < n4) {
    float4 v = ((const float4*)x)[i];
    bf16x4 o;
    o[0] = (__bf16)v.x; o[1] = (__bf16)v.y; o[2] = (__bf16)v.z; o[3] = (__bf16)v.w;
    ((bf16x4*)y)[i] = o;
  }
}

// W: [nm][E][E] fp32 (e,f) -> WT: [nm][E][E] bf16 transposed (f,e)
__global__ __launch_bounds__(256) void k_transpose_w(const float* __restrict__ W,
                                                     __bf16* __restrict__ WT) {
  __shared__ float tile[32][33];
  const float* Wm = W + (size_t)blockIdx.z * E_ * E_;
  __bf16* WTm = WT + (size_t)blockIdx.z * E_ * E_;
  int e0 = blockIdx.x * 32, f0 = blockIdx.y * 32;
  int tx = threadIdx.x & 31, ty = threadIdx.x >> 5;
  for (int i = ty; i < 32; i += 8) tile[i][tx] = Wm[(size_t)(e0 + i) * E_ + f0 + tx];
  __syncthreads();
  for (int i = ty; i < 32; i += 8) WTm[(size_t)(f0 + i) * E_ + e0 + tx] = (__bf16)tile[tx][i];
}

// v [b][h][s][d] -> vT [b][h][d][s]  (bf16)
__global__ __launch_bounds__(256) void k_transpose_v(const __bf16* __restrict__ v,
                                                     __bf16* __restrict__ vT) {
  __shared__ __bf16 tile[32][33];
  size_t bh = blockIdx.z;
  const __bf16* vp = v + bh * S_ * D_;
  __bf16* vtp = vT + bh * S_ * D_;
  int s0 = blockIdx.x * 32, d0 = blockIdx.y * 32;
  int tx = threadIdx.x & 31, ty = threadIdx.x >> 5;
  for (int i = ty; i < 32; i += 8) tile[i][tx] = vp[(size_t)(s0 + i) * D_ + d0 + tx];
  __syncthreads();
  for (int i = ty; i < 32; i += 8) vtp[(size_t)(d0 + i) * S_ + s0 + tx] = tile[tx][i];
}

// ---------------------------------------------------------------- RoPE + cache scatter
__global__ __launch_bounds__(256) void k_rope(__bf16* __restrict__ q, __bf16* __restrict__ k,
                                              const __bf16* __restrict__ v,
                                              const float* __restrict__ cosb,
                                              const float* __restrict__ sinb,
                                              const int* __restrict__ bt,
                                              float* __restrict__ kc, float* __restrict__ vc) {
  int idx = blockIdx.x * 256 + threadIdx.x;   // B*H*S*64 = 2^23 threads
  int j = idx & 63;
  int s = (idx >> 6) & (S_ - 1);
  int h = (idx >> 16) & (H_ - 1);
  int b = idx >> 21;
  size_t base = (((size_t)b * H_ + h) * S_ + s) * D_;
  float c  = cosb[(size_t)(b * S_ + s) * 64 + j];
  float sn = sinb[(size_t)(b * S_ + s) * 64 + j];
  float q1 = (float)q[base + j], q2 = (float)q[base + j + 64];
  float k1 = (float)k[base + j], k2 = (float)k[base + j + 64];
  float q1n = q1 * c - q2 * sn, q2n = q2 * c + q1 * sn;
  float k1n = k1 * c - k2 * sn, k2n = k2 * c + k1 * sn;
  q[base + j] = (__bf16)q1n; q[base + j + 64] = (__bf16)q2n;
  k[base + j] = (__bf16)k1n; k[base + j + 64] = (__bf16)k2n;
  int nb = s >> 4, sb = s & 15;
  int blk = bt[b * NB_ + nb];
  size_t cidx = (((size_t)blk * H_ + h) * BS_ + sb) * D_;
  kc[cidx + j] = k1n; kc[cidx + j + 64] = k2n;
  vc[cidx + j] = (float)v[base + j];
  vc[cidx + j + 64] = (float)v[base + j + 64];
}

// ---------------------------------------------------------------- GEMMs
// 256x256 tile, BK=32, 8 waves (2Mx4N), ring-4 LDS double-buffer, counted vmcnt.
// A: [M][K] bf16 row-major; BT: [N][K] bf16 row-major (i.e. B transposed).
// Schedule per K-tile t:
//   vmcnt(counted)  -- tile t landed (loads issued 3 tiles ago; 2 tiles stay in flight)
//   s_barrier       -- also publishes LDS; orders prev-tile reads vs upcoming writes
//   STAGE(t+3)      -- writes buf[(t+3)&3] == buf[(t-1)&3], whose reads finished last iter
//   ds_read frags, setprio(1), 32x MFMA, setprio(0)
// Ring of 4 buffers means in-flight staged writes never touch a buffer being read,
// so vmcnt never needs to drain to 0 in the main loop (T3/T4).

#define STAGE256(tt) {                                                             \
    int _b = (tt) & 3;                                                             \
    const __bf16* _ag = Ag + (size_t)(tt) * 32;                                    \
    const __bf16* _bg = Bg + (size_t)(tt) * 32;                                    \
    __bf16* _al = &ring[_b][0][0] + wid * 512 + lane * 8;                          \
    __bf16* _bl = &ring[_b][1][0] + wid * 512 + lane * 8;                          \
    gload_lds16(_ag, _al);                                                         \
    gload_lds16(_ag + (size_t)128 * E_, _al + 4096);                               \
    gload_lds16(_bg, _bl);                                                         \
    gload_lds16(_bg + (size_t)128 * E_, _bl + 4096);                               \
  }

#define COMPUTE256(tt) {                                                           \
    int _b = (tt) & 3;                                                             \
    const __bf16* _ab = &ring[_b][0][0];                                           \
    const __bf16* _bb = &ring[_b][1][0];                                           \
    bf16x8 afr[8], bfr[4];                                                         \
    _Pragma("unroll")                                                              \
    for (int i = 0; i < 8; i++)                                                    \
      afr[i] = *(const bf16x8*)&_ab[(wm * 128 + i * 16 + l15) * 32 + quad * 8];    \
    _Pragma("unroll")                                                              \
    for (int j = 0; j < 4; j++)                                                    \
      bfr[j] = *(const bf16x8*)&_bb[(wn * 64 + j * 16 + l15) * 32 + quad * 8];     \
    __builtin_amdgcn_s_setprio(1);                                                 \
    _Pragma("unroll")                                                              \
    for (int i = 0; i < 8; i++)                                                    \
      _Pragma("unroll")                                                            \
      for (int j = 0; j < 4; j++)                                                  \
        acc[i][j] = __builtin_amdgcn_mfma_f32_16x16x32_bf16(afr[i], bfr[j], acc[i][j], 0, 0, 0); \
    __builtin_amdgcn_s_setprio(0);                                                 \
  }

#define GEMM256_BODY                                                               \
  __shared__ __align__(16) __bf16 ring[4][2][256 * 32];  /* 128 KiB */             \
  int tid = threadIdx.x;                                                           \
  int wid = tid >> 6, lane = tid & 63, l15 = lane & 15, quad = lane >> 4;          \
  int wm = wid >> 2, wn = wid & 3;                                                 \
  /* T1: bijective XCD swizzle (gridDim.x % 8 == 0) */                             \
  int cpx = (int)gridDim.x >> 3;                                                   \
  int wg = ((int)blockIdx.x & 7) * cpx + ((int)blockIdx.x >> 3);                   \
  int m0 = (wg & 15) * 256, n0 = (wg >> 4) * 256;                                  \
  int srow = wid * 16 + (lane >> 2), scol = (lane & 3) * 8;                        \
  const __bf16* Ag = A + (size_t)(m0 + srow) * E_ + scol;                          \
  const __bf16* Bg = BT + (size_t)(n0 + srow) * E_ + scol;                         \
  f32x4 acc[8][4] = {};                                                            \
  STAGE256(0) STAGE256(1) STAGE256(2)                                              \
  for (int t = 0; t < NT_; ++t) {                                                  \
    if (t < NT_ - 2)       { asm volatile("s_waitcnt vmcnt(8)" ::: "memory"); }    \
    else if (t == NT_ - 2) { asm volatile("s_waitcnt vmcnt(4)" ::: "memory"); }    \
    else                   { asm volatile("s_waitcnt vmcnt(0)" ::: "memory"); }    \
    __builtin_amdgcn_s_barrier();                                                  \
    if (t + 3 < NT_) STAGE256(t + 3)                                               \
    COMPUTE256(t)                                                                  \
  }

__global__ __launch_bounds__(512, 1) void k_gemm_qkv(const __bf16* __restrict__ A,
                                                     const __bf16* __restrict__ BT,
                                                     __bf16* __restrict__ qkvb) {
  GEMM256_BODY
  for (int i = 0; i < 8; i++) {
    int tbase = m0 + wm * 128 + i * 16 + quad * 4;
    for (int j = 0; j < 4; j++) {
      int n = n0 + wn * 64 + j * 16 + l15;      // 0..12287
      int kk = n >> 12, nl = n & 4095;
      int h = nl >> 7, d = nl & 127;
      for (int r = 0; r < 4; r++) {
        int t = tbase + r;
        int bb = t >> 10, s = t & 1023;
        size_t idx = ((((size_t)kk * B_ + bb) * H_ + h) * S_ + s) * D_ + d;
        qkvb[idx] = (__bf16)acc[i][j][r];
      }
    }
  }
}

__global__ __launch_bounds__(512, 1) void k_gemm_out(const __bf16* __restrict__ A,
                                                     const __bf16* __restrict__ BT,
                                                     float* __restrict__ out) {
  GEMM256_BODY
  for (int i = 0; i < 8; i++) {
    int tbase = m0 + wm * 128 + i * 16 + quad * 4;
    for (int j = 0; j < 4; j++) {
      int n = n0 + wn * 64 + j * 16 + l15;
      for (int r = 0; r < 4; r++)
        out[(size_t)(tbase + r) * E_ + n] = acc[i][j][r];
    }
  }
}

// ---------------------------------------------------------------- flash attention
// q,k: [b][h][s][d] bf16 (post-RoPE); vT: [b][h][d][s] bf16; attn: [t][e] bf16
__global__ __launch_bounds__(256) void k_attn(const __bf16* __restrict__ q,
                                              const __bf16* __restrict__ k,
                                              const __bf16* __restrict__ vT,
                                              __bf16* __restrict__ attn) {
  __shared__ __align__(16) __bf16 Qs[64][136];
  __shared__ __align__(16) __bf16 Ks[64][136];
  __shared__ __align__(16) __bf16 Vs[128][72];
  __shared__ __align__(16) __bf16 Ps[4][16][72];

  int q0 = blockIdx.x * 64;
  int h = blockIdx.y, b = blockIdx.z;
  int tid = threadIdx.x, wid = tid >> 6, lane = tid & 63, l15 = lane & 15, quad = lane >> 4;

  size_t bh = (size_t)b * H_ + h;
  const __bf16* Qp = q + bh * S_ * D_;
  const __bf16* Kp = k + bh * S_ * D_;
  const __bf16* Vp = vT + bh * (size_t)D_ * S_;

  for (int c = tid; c < 1024; c += 256) {
    int r = c >> 4, dp = (c & 15) * 8;
    *(int4*)&Qs[r][dp] = *(const int4*)&Qp[(size_t)(q0 + r) * D_ + dp];
  }
  __syncthreads();
  bf16x8 aq[4];
  for (int ks = 0; ks < 4; ks++) aq[ks] = *(const bf16x8*)&Qs[wid * 16 + l15][ks * 32 + quad * 8];

  float m_run[4], l_run[4];
  f32x4 o_acc[8] = {};
  for (int r = 0; r < 4; r++) { m_run[r] = -1e30f; l_run[r] = 0.f; }
  const float sm_scale = 0.08838834764831845f;

  int kend = q0 + 64;
  for (int sk0 = 0; sk0 < kend; sk0 += 64) {
    __syncthreads();   // previous iter's Ks/Vs reads done
    for (int c = tid; c < 1024; c += 256) {
      int r = c >> 4, dp = (c & 15) * 8;
      *(int4*)&Ks[r][dp] = *(const int4*)&Kp[(size_t)(sk0 + r) * D_ + dp];
    }
    for (int c = tid; c < 1024; c += 256) {
      int d = c >> 3, sp = (c & 7) * 8;
      *(int4*)&Vs[d][sp] = *(const int4*)&Vp[(size_t)d * S_ + sk0 + sp];
    }
    __syncthreads();

    f32x4 st[4] = {};
    for (int nt = 0; nt < 4; nt++)
      for (int ks = 0; ks < 4; ks++) {
        bf16x8 bk = *(const bf16x8*)&Ks[nt * 16 + l15][ks * 32 + quad * 8];
        st[nt] = __builtin_amdgcn_mfma_f32_16x16x32_bf16(aq[ks], bk, st[nt], 0, 0, 0);
      }

    int qg = q0 + wid * 16 + quad * 4;
    float mnew[4], alpha[4];
    for (int r = 0; r < 4; r++) {
      float rmax = -1e30f;
      for (int nt = 0; nt < 4; nt++) {
        int kg = sk0 + nt * 16 + l15;
        float vsc = st[nt][r] * sm_scale;
        if (kg > qg + r) vsc = -1e30f;
        st[nt][r] = vsc;
        rmax = fmaxf(rmax, vsc);
      }
      for (int off = 1; off < 16; off <<= 1) rmax = fmaxf(rmax, __shfl_xor(rmax, off));
      mnew[r] = fmaxf(m_run[r], rmax);
      alpha[r] = __expf(m_run[r] - mnew[r]);
      float s_ = 0.f;
      for (int nt = 0; nt < 4; nt++) {
        float p = __expf(st[nt][r] - mnew[r]);
        st[nt][r] = p;
        s_ += p;
      }
      for (int off = 1; off < 16; off <<= 1) s_ += __shfl_xor(s_, off);
      l_run[r] = l_run[r] * alpha[r] + s_;
      m_run[r] = mnew[r];
    }

    for (int nt = 0; nt < 4; nt++)
      for (int r = 0; r < 4; r++)
        Ps[wid][quad * 4 + r][nt * 16 + l15] = (__bf16)st[nt][r];

    for (int dt = 0; dt < 8; dt++)
      for (int r = 0; r < 4; r++)
        o_acc[dt][r] *= alpha[r];

    __syncthreads();   // P visible; also keeps waves together

    for (int ks2 = 0; ks2 < 2; ks2++) {
      bf16x8 ap = *(const bf16x8*)&Ps[wid][l15][ks2 * 32 + quad * 8];
      for (int dt = 0; dt < 8; dt++) {
        bf16x8 bv = *(const bf16x8*)&Vs[dt * 16 + l15][ks2 * 32 + quad * 8];
        o_acc[dt] = __builtin_amdgcn_mfma_f32_16x16x32_bf16(ap, bv, o_acc[dt], 0, 0, 0);
      }
    }
  }

  size_t trow = (size_t)b * S_ + q0 + wid * 16 + quad * 4;
  for (int dt = 0; dt < 8; dt++) {
    int e = h * D_ + dt * 16 + l15;
    for (int r = 0; r < 4; r++) {
      float val = o_acc[dt][r] / l_run[r];
      attn[(trow + r) * E_ + e] = (__bf16)val;
    }
  }
}

// ---------------------------------------------------------------- launch
extern "C" void kernel_launch(void* const* d_in, const int* in_sizes, int n_in,
                              void* d_out, int out_size, void* d_ws, size_t ws_size,
                              hipStream_t stream) {
  const float* hs    = (const float*)d_in[0];
  const float* qkv_w = (const float*)d_in[1];
  const float* o_w   = (const float*)d_in[2];
  const float* cosb  = (const float*)d_in[3];
  const float* sinb  = (const float*)d_in[4];
  const int*   bt    = (const int*)d_in[7];

  float* out = (float*)d_out;
  float* kc  = out + (size_t)T_ * E_;
  float* vc  = kc + (size_t)B_ * NB_ * H_ * BS_ * D_;

  // ws layout (288 MB): [hsb/attn 32MB][wT 96MB][oT 32MB][q 32][k 32][v 32][vT 32]
  char* ws = (char*)d_ws;
  __bf16* hsb  = (__bf16*)ws;
  __bf16* wT   = (__bf16*)(ws + 33554432);
  __bf16* oT   = wT + (size_t)3 * E_ * E_;
  __bf16* qb   = (__bf16*)(ws + 167772160);
  __bf16* kb   = qb + (size_t)B_ * H_ * S_ * D_;
  __bf16* vb   = kb + (size_t)B_ * H_ * S_ * D_;
  __bf16* vTt  = (__bf16*)(ws + 268435456);
  __bf16* attn = hsb;  // hs no longer needed once attention runs

  k_convert_hs<<<dim3(T_ * E_ / 4 / 256), dim3(256), 0, stream>>>(hs, hsb, T_ * E_ / 4);
  k_transpose_w<<<dim3(128, 128, 3), dim3(256), 0, stream>>>(qkv_w, wT);
  k_transpose_w<<<dim3(128, 128, 1), dim3(256), 0, stream>>>(o_w, oT);
  k_gemm_qkv<<<dim3(768), dim3(512), 0, stream>>>(hsb, wT, qb);
  k_rope<<<dim3(32768), dim3(256), 0, stream>>>(qb, kb, vb, cosb, sinb, bt, kc, vc);
  k_transpose_v<<<dim3(32, 4, 128), dim3(256), 0, stream>>>(vb, vTt);
  k_attn<<<dim3(16, 32, 4), dim3(256), 0, stream>>>(qb, kb, vTt, attn);
  k_gemm_out<<<dim3(256), dim3(512), 0, stream>>>(attn, oT, out);
}

// Round 2
// 1328.663 us; speedup vs baseline: 1.1507x; 1.0223x over previous
//
#include <hip/hip_runtime.h>

#define B_  4
#define S_  1024
#define H_  32
#define D_  128
#define E_  4096
#define T_  4096
#define NB_ 64
#define BS_ 16
#define NT_ 128   // K-tiles of 32 over K=4096

typedef __attribute__((ext_vector_type(8))) __bf16 bf16x8;
typedef __attribute__((ext_vector_type(4))) __bf16 bf16x4;
typedef __attribute__((ext_vector_type(4))) float f32x4;

__device__ __forceinline__ void gload_lds16(const __bf16* g, __bf16* l) {
  __builtin_amdgcn_global_load_lds((const __attribute__((address_space(1))) void*)g,
                                   (__attribute__((address_space(3))) void*)l, 16, 0, 0);
}

// ---------------------------------------------------------------- converts
__global__ __launch_bounds__(256) void k_convert_hs(const float* __restrict__ x,
                                                    __bf16* __restrict__ y, int n4) {
  int i = blockIdx.x * 256 + threadIdx.x;
  if (i < n4) {
    float4 v = ((const float4*)x)[i];
    bf16x4 o;
    o[0] = (__bf16)v.x; o[1] = (__bf16)v.y; o[2] = (__bf16)v.z; o[3] = (__bf16)v.w;
    ((bf16x4*)y)[i] = o;
  }
}

// W: [nm][E][E] fp32 (e,f) -> WT: [nm][E][E] bf16 transposed (f,e)
__global__ __launch_bounds__(256) void k_transpose_w(const float* __restrict__ W,
                                                     __bf16* __restrict__ WT) {
  __shared__ float tile[32][33];
  const float* Wm = W + (size_t)blockIdx.z * E_ * E_;
  __bf16* WTm = WT + (size_t)blockIdx.z * E_ * E_;
  int e0 = blockIdx.x * 32, f0 = blockIdx.y * 32;
  int tx = threadIdx.x & 31, ty = threadIdx.x >> 5;
  for (int i = ty; i < 32; i += 8) tile[i][tx] = Wm[(size_t)(e0 + i) * E_ + f0 + tx];
  __syncthreads();
  for (int i = ty; i < 32; i += 8) WTm[(size_t)(f0 + i) * E_ + e0 + tx] = (__bf16)tile[tx][i];
}

// v [b][h][s][d] -> vT [b][h][d][s]  (bf16)
__global__ __launch_bounds__(256) void k_transpose_v(const __bf16* __restrict__ v,
                                                     __bf16* __restrict__ vT) {
  __shared__ __bf16 tile[32][33];
  size_t bh = blockIdx.z;
  const __bf16* vp = v + bh * S_ * D_;
  __bf16* vtp = vT + bh * S_ * D_;
  int s0 = blockIdx.x * 32, d0 = blockIdx.y * 32;
  int tx = threadIdx.x & 31, ty = threadIdx.x >> 5;
  for (int i = ty; i < 32; i += 8) tile[i][tx] = vp[(size_t)(s0 + i) * D_ + d0 + tx];
  __syncthreads();
  for (int i = ty; i < 32; i += 8) vtp[(size_t)(d0 + i) * S_ + s0 + tx] = tile[tx][i];
}

// ---------------------------------------------------------------- RoPE + cache scatter
__global__ __launch_bounds__(256) void k_rope(__bf16* __restrict__ q, __bf16* __restrict__ k,
                                              const __bf16* __restrict__ v,
                                              const float* __restrict__ cosb,
                                              const float* __restrict__ sinb,
                                              const int* __restrict__ bt,
                                              float* __restrict__ kc, float* __restrict__ vc) {
  int idx = blockIdx.x * 256 + threadIdx.x;   // B*H*S*64 = 2^23 threads
  int j = idx & 63;
  int s = (idx >> 6) & (S_ - 1);
  int h = (idx >> 16) & (H_ - 1);
  int b = idx >> 21;
  size_t base = (((size_t)b * H_ + h) * S_ + s) * D_;
  float c  = cosb[(size_t)(b * S_ + s) * 64 + j];
  float sn = sinb[(size_t)(b * S_ + s) * 64 + j];
  float q1 = (float)q[base + j], q2 = (float)q[base + j + 64];
  float k1 = (float)k[base + j], k2 = (float)k[base + j + 64];
  float q1n = q1 * c - q2 * sn, q2n = q2 * c + q1 * sn;
  float k1n = k1 * c - k2 * sn, k2n = k2 * c + k1 * sn;
  q[base + j] = (__bf16)q1n; q[base + j + 64] = (__bf16)q2n;
  k[base + j] = (__bf16)k1n; k[base + j + 64] = (__bf16)k2n;
  int nb = s >> 4, sb = s & 15;
  int blk = bt[b * NB_ + nb];
  size_t cidx = (((size_t)blk * H_ + h) * BS_ + sb) * D_;
  kc[cidx + j] = k1n; kc[cidx + j + 64] = k2n;
  vc[cidx + j] = (float)v[base + j];
  vc[cidx + j + 64] = (float)v[base + j + 64];
}

// ---------------------------------------------------------------- GEMMs
// 256x256 tile, BK=32, 8 waves (2Mx4N), ring-4 LDS buffers, counted vmcnt (T3/T4),
// setprio around MFMA cluster (T5), XCD swizzle (T1), and T2 LDS bank swizzle.
//
// T2 swizzle (rule #21: both-sides-or-neither with global_load_lds):
//   LDS rows are 64B (32 bf16). Physical 16B chunk c_phys = c_log ^ ((row>>1)&3).
//   - LDS dest stays LINEAR (global_load_lds writes base+lane*16).
//   - Global SOURCE is pre-swizzled: lane writing phys chunk (lane&3) of row
//     (wid*16 + (lane>>2)) loads logical chunk (lane&3)^((lane>>3)&3).
//   - ds_read col offset: quad*8 -> (quad ^ ((l15>>1)&3))*8.
//   Row-mod-8 is preserved by the +128-row staging half and the 16-row fragment
//   steps, so both XOR terms are per-thread constants (zero loop VALU cost).
//   Result: 16 lanes/quad spread over all 8 16B bank-groups -> 2-way (free).

#define STAGE256(tt) {                                                             \
    int _b = (tt) & 3;                                                             \
    const __bf16* _ag = Ag + (size_t)(tt) * 32;                                    \
    const __bf16* _bg = Bg + (size_t)(tt) * 32;                                    \
    __bf16* _al = &ring[_b][0][0] + wid * 512 + lane * 8;                          \
    __bf16* _bl = &ring[_b][1][0] + wid * 512 + lane * 8;                          \
    gload_lds16(_ag, _al);                                                         \
    gload_lds16(_ag + (size_t)128 * E_, _al + 4096);                               \
    gload_lds16(_bg, _bl);                                                         \
    gload_lds16(_bg + (size_t)128 * E_, _bl + 4096);                               \
  }

#define COMPUTE256(tt) {                                                           \
    int _b = (tt) & 3;                                                             \
    const __bf16* _ab = &ring[_b][0][0];                                           \
    const __bf16* _bb = &ring[_b][1][0];                                           \
    bf16x8 afr[8], bfr[4];                                                         \
    _Pragma("unroll")                                                              \
    for (int i = 0; i < 8; i++)                                                    \
      afr[i] = *(const bf16x8*)&_ab[(wm * 128 + i * 16 + l15) * 32 + rdoff];       \
    _Pragma("unroll")                                                              \
    for (int j = 0; j < 4; j++)                                                    \
      bfr[j] = *(const bf16x8*)&_bb[(wn * 64 + j * 16 + l15) * 32 + rdoff];        \
    __builtin_amdgcn_s_setprio(1);                                                 \
    _Pragma("unroll")                                                              \
    for (int i = 0; i < 8; i++)                                                    \
      _Pragma("unroll")                                                            \
      for (int j = 0; j < 4; j++)                                                  \
        acc[i][j] = __builtin_amdgcn_mfma_f32_16x16x32_bf16(afr[i], bfr[j], acc[i][j], 0, 0, 0); \
    __builtin_amdgcn_s_setprio(0);                                                 \
  }

#define GEMM256_BODY                                                               \
  __shared__ __align__(16) __bf16 ring[4][2][256 * 32];  /* 128 KiB */             \
  int tid = threadIdx.x;                                                           \
  int wid = tid >> 6, lane = tid & 63, l15 = lane & 15, quad = lane >> 4;          \
  int wm = wid >> 2, wn = wid & 3;                                                 \
  int rdoff = (quad ^ ((l15 >> 1) & 3)) * 8;      /* T2 swizzled read column */    \
  /* T1: bijective XCD swizzle (gridDim.x % 8 == 0) */                             \
  int cpx = (int)gridDim.x >> 3;                                                   \
  int wg = ((int)blockIdx.x & 7) * cpx + ((int)blockIdx.x >> 3);                   \
  int m0 = (wg & 15) * 256, n0 = (wg >> 4) * 256;                                  \
  int srow = wid * 16 + (lane >> 2);                                               \
  int scol = (((lane & 3) ^ ((lane >> 3) & 3)) * 8);  /* inverse-swz source col */ \
  const __bf16* Ag = A + (size_t)(m0 + srow) * E_ + scol;                          \
  const __bf16* Bg = BT + (size_t)(n0 + srow) * E_ + scol;                         \
  f32x4 acc[8][4] = {};                                                            \
  STAGE256(0) STAGE256(1) STAGE256(2)                                              \
  for (int t = 0; t < NT_; ++t) {                                                  \
    if (t < NT_ - 2)       { asm volatile("s_waitcnt vmcnt(8)" ::: "memory"); }    \
    else if (t == NT_ - 2) { asm volatile("s_waitcnt vmcnt(4)" ::: "memory"); }    \
    else                   { asm volatile("s_waitcnt vmcnt(0)" ::: "memory"); }    \
    __builtin_amdgcn_s_barrier();                                                  \
    if (t + 3 < NT_) STAGE256(t + 3)                                               \
    COMPUTE256(t)                                                                  \
  }

__global__ __launch_bounds__(512, 1) void k_gemm_qkv(const __bf16* __restrict__ A,
                                                     const __bf16* __restrict__ BT,
                                                     __bf16* __restrict__ qkvb) {
  GEMM256_BODY
  for (int i = 0; i < 8; i++) {
    int tbase = m0 + wm * 128 + i * 16 + quad * 4;
    for (int j = 0; j < 4; j++) {
      int n = n0 + wn * 64 + j * 16 + l15;      // 0..12287
      int kk = n >> 12, nl = n & 4095;
      int h = nl >> 7, d = nl & 127;
      for (int r = 0; r < 4; r++) {
        int t = tbase + r;
        int bb = t >> 10, s = t & 1023;
        size_t idx = ((((size_t)kk * B_ + bb) * H_ + h) * S_ + s) * D_ + d;
        qkvb[idx] = (__bf16)acc[i][j][r];
      }
    }
  }
}

__global__ __launch_bounds__(512, 1) void k_gemm_out(const __bf16* __restrict__ A,
                                                     const __bf16* __restrict__ BT,
                                                     float* __restrict__ out) {
  GEMM256_BODY
  for (int i = 0; i < 8; i++) {
    int tbase = m0 + wm * 128 + i * 16 + quad * 4;
    for (int j = 0; j < 4; j++) {
      int n = n0 + wn * 64 + j * 16 + l15;
      for (int r = 0; r < 4; r++)
        out[(size_t)(tbase + r) * E_ + n] = acc[i][j][r];
    }
  }
}

// ---------------------------------------------------------------- flash attention
// q,k: [b][h][s][d] bf16 (post-RoPE); vT: [b][h][d][s] bf16; attn: [t][e] bf16
__global__ __launch_bounds__(256) void k_attn(const __bf16* __restrict__ q,
                                              const __bf16* __restrict__ k,
                                              const __bf16* __restrict__ vT,
                                              __bf16* __restrict__ attn) {
  __shared__ __align__(16) __bf16 Qs[64][136];
  __shared__ __align__(16) __bf16 Ks[64][136];
  __shared__ __align__(16) __bf16 Vs[128][72];
  __shared__ __align__(16) __bf16 Ps[4][16][72];

  int q0 = blockIdx.x * 64;
  int h = blockIdx.y, b = blockIdx.z;
  int tid = threadIdx.x, wid = tid >> 6, lane = tid & 63, l15 = lane & 15, quad = lane >> 4;

  size_t bh = (size_t)b * H_ + h;
  const __bf16* Qp = q + bh * S_ * D_;
  const __bf16* Kp = k + bh * S_ * D_;
  const __bf16* Vp = vT + bh * (size_t)D_ * S_;

  for (int c = tid; c < 1024; c += 256) {
    int r = c >> 4, dp = (c & 15) * 8;
    *(int4*)&Qs[r][dp] = *(const int4*)&Qp[(size_t)(q0 + r) * D_ + dp];
  }
  __syncthreads();
  bf16x8 aq[4];
  for (int ks = 0; ks < 4; ks++) aq[ks] = *(const bf16x8*)&Qs[wid * 16 + l15][ks * 32 + quad * 8];

  float m_run[4], l_run[4];
  f32x4 o_acc[8] = {};
  for (int r = 0; r < 4; r++) { m_run[r] = -1e30f; l_run[r] = 0.f; }
  const float sm_scale = 0.08838834764831845f;

  int kend = q0 + 64;
  for (int sk0 = 0; sk0 < kend; sk0 += 64) {
    __syncthreads();   // previous iter's Ks/Vs reads done
    for (int c = tid; c < 1024; c += 256) {
      int r = c >> 4, dp = (c & 15) * 8;
      *(int4*)&Ks[r][dp] = *(const int4*)&Kp[(size_t)(sk0 + r) * D_ + dp];
    }
    for (int c = tid; c < 1024; c += 256) {
      int d = c >> 3, sp = (c & 7) * 8;
      *(int4*)&Vs[d][sp] = *(const int4*)&Vp[(size_t)d * S_ + sk0 + sp];
    }
    __syncthreads();

    f32x4 st[4] = {};
    for (int nt = 0; nt < 4; nt++)
      for (int ks = 0; ks < 4; ks++) {
        bf16x8 bk = *(const bf16x8*)&Ks[nt * 16 + l15][ks * 32 + quad * 8];
        st[nt] = __builtin_amdgcn_mfma_f32_16x16x32_bf16(aq[ks], bk, st[nt], 0, 0, 0);
      }

    int qg = q0 + wid * 16 + quad * 4;
    float mnew[4], alpha[4];
    for (int r = 0; r < 4; r++) {
      float rmax = -1e30f;
      for (int nt = 0; nt < 4; nt++) {
        int kg = sk0 + nt * 16 + l15;
        float vsc = st[nt][r] * sm_scale;
        if (kg > qg + r) vsc = -1e30f;
        st[nt][r] = vsc;
        rmax = fmaxf(rmax, vsc);
      }
      for (int off = 1; off < 16; off <<= 1) rmax = fmaxf(rmax, __shfl_xor(rmax, off));
      mnew[r] = fmaxf(m_run[r], rmax);
      alpha[r] = __expf(m_run[r] - mnew[r]);
      float s_ = 0.f;
      for (int nt = 0; nt < 4; nt++) {
        float p = __expf(st[nt][r] - mnew[r]);
        st[nt][r] = p;
        s_ += p;
      }
      for (int off = 1; off < 16; off <<= 1) s_ += __shfl_xor(s_, off);
      l_run[r] = l_run[r] * alpha[r] + s_;
      m_run[r] = mnew[r];
    }

    for (int nt = 0; nt < 4; nt++)
      for (int r = 0; r < 4; r++)
        Ps[wid][quad * 4 + r][nt * 16 + l15] = (__bf16)st[nt][r];

    for (int dt = 0; dt < 8; dt++)
      for (int r = 0; r < 4; r++)
        o_acc[dt][r] *= alpha[r];

    __syncthreads();   // P visible; also keeps waves together

    for (int ks2 = 0; ks2 < 2; ks2++) {
      bf16x8 ap = *(const bf16x8*)&Ps[wid][l15][ks2 * 32 + quad * 8];
      for (int dt = 0; dt < 8; dt++) {
        bf16x8 bv = *(const bf16x8*)&Vs[dt * 16 + l15][ks2 * 32 + quad * 8];
        o_acc[dt] = __builtin_amdgcn_mfma_f32_16x16x32_bf16(ap, bv, o_acc[dt], 0, 0, 0);
      }
    }
  }

  size_t trow = (size_t)b * S_ + q0 + wid * 16 + quad * 4;
  for (int dt = 0; dt < 8; dt++) {
    int e = h * D_ + dt * 16 + l15;
    for (int r = 0; r < 4; r++) {
      float val = o_acc[dt][r] / l_run[r];
      attn[(trow + r) * E_ + e] = (__bf16)val;
    }
  }
}

// ---------------------------------------------------------------- launch
extern "C" void kernel_launch(void* const* d_in, const int* in_sizes, int n_in,
                              void* d_out, int out_size, void* d_ws, size_t ws_size,
                              hipStream_t stream) {
  const float* hs    = (const float*)d_in[0];
  const float* qkv_w = (const float*)d_in[1];
  const float* o_w   = (const float*)d_in[2];
  const float* cosb  = (const float*)d_in[3];
  const float* sinb  = (const float*)d_in[4];
  const int*   bt    = (const int*)d_in[7];

  float* out = (float*)d_out;
  float* kc  = out + (size_t)T_ * E_;
  float* vc  = kc + (size_t)B_ * NB_ * H_ * BS_ * D_;

  // ws layout (288 MB): [hsb/attn 32MB][wT 96MB][oT 32MB][q 32][k 32][v 32][vT 32]
  char* ws = (char*)d_ws;
  __bf16* hsb  = (__bf16*)ws;
  __bf16* wT   = (__bf16*)(ws + 33554432);
  __bf16* oT   = wT + (size_t)3 * E_ * E_;
  __bf16* qb   = (__bf16*)(ws + 167772160);
  __bf16* kb   = qb + (size_t)B_ * H_ * S_ * D_;
  __bf16* vb   = kb + (size_t)B_ * H_ * S_ * D_;
  __bf16* vTt  = (__bf16*)(ws + 268435456);
  __bf16* attn = hsb;  // hs no longer needed once attention runs

  k_convert_hs<<<dim3(T_ * E_ / 4 / 256), dim3(256), 0, stream>>>(hs, hsb, T_ * E_ / 4);
  k_transpose_w<<<dim3(128, 128, 3), dim3(256), 0, stream>>>(qkv_w, wT);
  k_transpose_w<<<dim3(128, 128, 1), dim3(256), 0, stream>>>(o_w, oT);
  k_gemm_qkv<<<dim3(768), dim3(512), 0, stream>>>(hsb, wT, qb);
  k_rope<<<dim3(32768), dim3(256), 0, stream>>>(qb, kb, vb, cosb, sinb, bt, kc, vc);
  k_transpose_v<<<dim3(32, 4, 128), dim3(256), 0, stream>>>(vb, vTt);
  k_attn<<<dim3(16, 32, 4), dim3(256), 0, stream>>>(qb, kb, vTt, attn);
  k_gemm_out<<<dim3(256), dim3(512), 0, stream>>>(attn, oT, out);
}

// Round 3
// 1300.337 us; speedup vs baseline: 1.1758x; 1.0218x over previous
//
#include <hip/hip_runtime.h>

#define B_  4
#define S_  1024
#define H_  32
#define D_  128
#define E_  4096
#define T_  4096
#define NB_ 64
#define BS_ 16
#define NT_ 128   // K-tiles of 32 over K=4096

typedef __attribute__((ext_vector_type(8))) __bf16 bf16x8;
typedef __attribute__((ext_vector_type(4))) __bf16 bf16x4;
typedef __attribute__((ext_vector_type(4))) float f32x4;

__device__ __forceinline__ void gload_lds16(const __bf16* g, __bf16* l) {
  __builtin_amdgcn_global_load_lds((const __attribute__((address_space(1))) void*)g,
                                   (__attribute__((address_space(3))) void*)l, 16, 0, 0);
}

// ---------------------------------------------------------------- converts
__global__ __launch_bounds__(256) void k_convert_hs(const float* __restrict__ x,
                                                    __bf16* __restrict__ y, int n4) {
  int i = blockIdx.x * 256 + threadIdx.x;
  if (i < n4) {
    float4 v = ((const float4*)x)[i];
    bf16x4 o;
    o[0] = (__bf16)v.x; o[1] = (__bf16)v.y; o[2] = (__bf16)v.z; o[3] = (__bf16)v.w;
    ((bf16x4*)y)[i] = o;
  }
}

// W: [nm][E][E] fp32 (e,f) -> WT: [nm][E][E] bf16 transposed (f,e)
// Vectorized: float4 loads, bf16x4 stores, one pass each.
__global__ __launch_bounds__(256) void k_transpose_w(const float* __restrict__ W,
                                                     __bf16* __restrict__ WT) {
  __shared__ float tile[32][33];
  const float* Wm = W + (size_t)blockIdx.z * E_ * E_;
  __bf16* WTm = WT + (size_t)blockIdx.z * E_ * E_;
  int e0 = blockIdx.x * 32, f0 = blockIdx.y * 32;
  int r = threadIdx.x >> 3, c = threadIdx.x & 7;
  float4 v = *(const float4*)&Wm[(size_t)(e0 + r) * E_ + f0 + c * 4];
  tile[r][c * 4 + 0] = v.x; tile[r][c * 4 + 1] = v.y;
  tile[r][c * 4 + 2] = v.z; tile[r][c * 4 + 3] = v.w;
  __syncthreads();
  bf16x4 o;
  o[0] = (__bf16)tile[c * 4 + 0][r];
  o[1] = (__bf16)tile[c * 4 + 1][r];
  o[2] = (__bf16)tile[c * 4 + 2][r];
  o[3] = (__bf16)tile[c * 4 + 3][r];
  *(bf16x4*)&WTm[(size_t)(f0 + r) * E_ + e0 + c * 4] = o;
}

// v [b][h][s][d] -> vT [b][h][d][s]  (bf16)
__global__ __launch_bounds__(256) void k_transpose_v(const __bf16* __restrict__ v,
                                                     __bf16* __restrict__ vT) {
  __shared__ __bf16 tile[32][33];
  size_t bh = blockIdx.z;
  const __bf16* vp = v + bh * S_ * D_;
  __bf16* vtp = vT + bh * S_ * D_;
  int s0 = blockIdx.x * 32, d0 = blockIdx.y * 32;
  int tx = threadIdx.x & 31, ty = threadIdx.x >> 5;
  for (int i = ty; i < 32; i += 8) tile[i][tx] = vp[(size_t)(s0 + i) * D_ + d0 + tx];
  __syncthreads();
  for (int i = ty; i < 32; i += 8) vtp[(size_t)(d0 + i) * S_ + s0 + tx] = tile[tx][i];
}

// ---------------------------------------------------------------- RoPE + cache scatter
__global__ __launch_bounds__(256) void k_rope(__bf16* __restrict__ q, __bf16* __restrict__ k,
                                              const __bf16* __restrict__ v,
                                              const float* __restrict__ cosb,
                                              const float* __restrict__ sinb,
                                              const int* __restrict__ bt,
                                              float* __restrict__ kc, float* __restrict__ vc) {
  int idx = blockIdx.x * 256 + threadIdx.x;   // B*H*S*64 = 2^23 threads
  int j = idx & 63;
  int s = (idx >> 6) & (S_ - 1);
  int h = (idx >> 16) & (H_ - 1);
  int b = idx >> 21;
  size_t base = (((size_t)b * H_ + h) * S_ + s) * D_;
  float c  = cosb[(size_t)(b * S_ + s) * 64 + j];
  float sn = sinb[(size_t)(b * S_ + s) * 64 + j];
  float q1 = (float)q[base + j], q2 = (float)q[base + j + 64];
  float k1 = (float)k[base + j], k2 = (float)k[base + j + 64];
  float q1n = q1 * c - q2 * sn, q2n = q2 * c + q1 * sn;
  float k1n = k1 * c - k2 * sn, k2n = k2 * c + k1 * sn;
  q[base + j] = (__bf16)q1n; q[base + j + 64] = (__bf16)q2n;
  k[base + j] = (__bf16)k1n; k[base + j + 64] = (__bf16)k2n;
  int nb = s >> 4, sb = s & 15;
  int blk = bt[b * NB_ + nb];
  size_t cidx = (((size_t)blk * H_ + h) * BS_ + sb) * D_;
  kc[cidx + j] = k1n; kc[cidx + j + 64] = k2n;
  vc[cidx + j] = (float)v[base + j];
  vc[cidx + j + 64] = (float)v[base + j + 64];
}

// ---------------------------------------------------------------- GEMMs
// 256x256 tile, BK=32, 8 waves (2Mx4N), ring-4 LDS buffers, counted vmcnt (T3/T4),
// setprio around MFMA (T5), XCD swizzle (T1), T2 LDS bank swizzle, and intra-tile
// phase pipelining: 4 phases of 8 MFMA; each phase issues the NEXT A-pair's
// ds_reads before its MFMA cluster so the LDS pipe overlaps the MFMA pipe
// (R2 showed all-reads-then-all-MFMA serializes the two: ~2450cy/tile vs
// LDS ~1156 + MFMA ~1030). sched_barrier(0) between phases stops the compiler
// from re-bunching the reads at the top. Same dep structure as R2 (all reads
// of tile t after barrier t; vmcnt ring unchanged) -> no new race surface.
//
// T2 swizzle (rule #21: both-sides-or-neither with global_load_lds):
//   phys 16B chunk = logical chunk ^ ((row>>1)&3); LDS dest linear,
//   global source pre-swizzled, ds_read col offset swizzled the same way.

#define STAGE256(tt) {                                                             \
    int _b = (tt) & 3;                                                             \
    const __bf16* _ag = Ag + (size_t)(tt) * 32;                                    \
    const __bf16* _bg = Bg + (size_t)(tt) * 32;                                    \
    __bf16* _al = &ring[_b][0][0] + wid * 512 + lane * 8;                          \
    __bf16* _bl = &ring[_b][1][0] + wid * 512 + lane * 8;                          \
    gload_lds16(_ag, _al);                                                         \
    gload_lds16(_ag + (size_t)128 * E_, _al + 4096);                               \
    gload_lds16(_bg, _bl);                                                         \
    gload_lds16(_bg + (size_t)128 * E_, _bl + 4096);                               \
  }

#define COMPUTE256(tt) {                                                           \
    int _b = (tt) & 3;                                                             \
    const __bf16* _ab = &ring[_b][0][0] + (wm * 128 + l15) * 32 + rdoff;           \
    const __bf16* _bb = &ring[_b][1][0] + (wn * 64 + l15) * 32 + rdoff;            \
    bf16x8 bfr[4];                                                                 \
    _Pragma("unroll")                                                              \
    for (int j = 0; j < 4; j++) bfr[j] = *(const bf16x8*)&_bb[j * 512];            \
    bf16x8 a0 = *(const bf16x8*)&_ab[0];                                           \
    bf16x8 a1 = *(const bf16x8*)&_ab[512];                                         \
    __builtin_amdgcn_s_setprio(1);                                                 \
    _Pragma("unroll")                                                              \
    for (int p = 0; p < 4; p++) {                                                  \
      bf16x8 n0 = {}, n1 = {};                                                     \
      if (p < 3) {                                                                 \
        n0 = *(const bf16x8*)&_ab[(2 * p + 2) * 512];                              \
        n1 = *(const bf16x8*)&_ab[(2 * p + 3) * 512];                              \
      }                                                                            \
      _Pragma("unroll")                                                            \
      for (int j = 0; j < 4; j++)                                                  \
        acc[2 * p][j] = __builtin_amdgcn_mfma_f32_16x16x32_bf16(a0, bfr[j], acc[2 * p][j], 0, 0, 0); \
      _Pragma("unroll")                                                            \
      for (int j = 0; j < 4; j++)                                                  \
        acc[2 * p + 1][j] = __builtin_amdgcn_mfma_f32_16x16x32_bf16(a1, bfr[j], acc[2 * p + 1][j], 0, 0, 0); \
      __builtin_amdgcn_sched_barrier(0);                                           \
      if (p < 3) { a0 = n0; a1 = n1; }                                             \
    }                                                                              \
    __builtin_amdgcn_s_setprio(0);                                                 \
  }

#define GEMM256_BODY                                                               \
  __shared__ __align__(16) __bf16 ring[4][2][256 * 32];  /* 128 KiB */             \
  int tid = threadIdx.x;                                                           \
  int wid = tid >> 6, lane = tid & 63, l15 = lane & 15, quad = lane >> 4;          \
  int wm = wid >> 2, wn = wid & 3;                                                 \
  int rdoff = (quad ^ ((l15 >> 1) & 3)) * 8;      /* T2 swizzled read column */    \
  /* T1: bijective XCD swizzle (gridDim.x % 8 == 0) */                             \
  int cpx = (int)gridDim.x >> 3;                                                   \
  int wg = ((int)blockIdx.x & 7) * cpx + ((int)blockIdx.x >> 3);                   \
  int m0 = (wg & 15) * 256, n0 = (wg >> 4) * 256;                                  \
  int srow = wid * 16 + (lane >> 2);                                               \
  int scol = (((lane & 3) ^ ((lane >> 3) & 3)) * 8);  /* inverse-swz source col */ \
  const __bf16* Ag = A + (size_t)(m0 + srow) * E_ + scol;                          \
  const __bf16* Bg = BT + (size_t)(n0 + srow) * E_ + scol;                         \
  f32x4 acc[8][4] = {};                                                            \
  STAGE256(0) STAGE256(1) STAGE256(2)                                              \
  for (int t = 0; t < NT_; ++t) {                                                  \
    if (t < NT_ - 2)       { asm volatile("s_waitcnt vmcnt(8)" ::: "memory"); }    \
    else if (t == NT_ - 2) { asm volatile("s_waitcnt vmcnt(4)" ::: "memory"); }    \
    else                   { asm volatile("s_waitcnt vmcnt(0)" ::: "memory"); }    \
    __builtin_amdgcn_s_barrier();                                                  \
    if (t + 3 < NT_) STAGE256(t + 3)                                               \
    COMPUTE256(t)                                                                  \
  }

__global__ __launch_bounds__(512, 1) void k_gemm_qkv(const __bf16* __restrict__ A,
                                                     const __bf16* __restrict__ BT,
                                                     __bf16* __restrict__ qkvb) {
  GEMM256_BODY
  for (int i = 0; i < 8; i++) {
    int tbase = m0 + wm * 128 + i * 16 + quad * 4;
    for (int j = 0; j < 4; j++) {
      int n = n0 + wn * 64 + j * 16 + l15;      // 0..12287
      int kk = n >> 12, nl = n & 4095;
      int h = nl >> 7, d = nl & 127;
      for (int r = 0; r < 4; r++) {
        int t = tbase + r;
        int bb = t >> 10, s = t & 1023;
        size_t idx = ((((size_t)kk * B_ + bb) * H_ + h) * S_ + s) * D_ + d;
        qkvb[idx] = (__bf16)acc[i][j][r];
      }
    }
  }
}

__global__ __launch_bounds__(512, 1) void k_gemm_out(const __bf16* __restrict__ A,
                                                     const __bf16* __restrict__ BT,
                                                     float* __restrict__ out) {
  GEMM256_BODY
  for (int i = 0; i < 8; i++) {
    int tbase = m0 + wm * 128 + i * 16 + quad * 4;
    for (int j = 0; j < 4; j++) {
      int n = n0 + wn * 64 + j * 16 + l15;
      for (int r = 0; r < 4; r++)
        out[(size_t)(tbase + r) * E_ + n] = acc[i][j][r];
    }
  }
}

// ---------------------------------------------------------------- flash attention
// q,k: [b][h][s][d] bf16 (post-RoPE); vT: [b][h][d][s] bf16; attn: [t][e] bf16
__global__ __launch_bounds__(256) void k_attn(const __bf16* __restrict__ q,
                                              const __bf16* __restrict__ k,
                                              const __bf16* __restrict__ vT,
                                              __bf16* __restrict__ attn) {
  __shared__ __align__(16) __bf16 Qs[64][136];
  __shared__ __align__(16) __bf16 Ks[64][136];
  __shared__ __align__(16) __bf16 Vs[128][72];
  __shared__ __align__(16) __bf16 Ps[4][16][72];

  int q0 = blockIdx.x * 64;
  int h = blockIdx.y, b = blockIdx.z;
  int tid = threadIdx.x, wid = tid >> 6, lane = tid & 63, l15 = lane & 15, quad = lane >> 4;

  size_t bh = (size_t)b * H_ + h;
  const __bf16* Qp = q + bh * S_ * D_;
  const __bf16* Kp = k + bh * S_ * D_;
  const __bf16* Vp = vT + bh * (size_t)D_ * S_;

  for (int c = tid; c < 1024; c += 256) {
    int r = c >> 4, dp = (c & 15) * 8;
    *(int4*)&Qs[r][dp] = *(const int4*)&Qp[(size_t)(q0 + r) * D_ + dp];
  }
  __syncthreads();
  bf16x8 aq[4];
  for (int ks = 0; ks < 4; ks++) aq[ks] = *(const bf16x8*)&Qs[wid * 16 + l15][ks * 32 + quad * 8];

  float m_run[4], l_run[4];
  f32x4 o_acc[8] = {};
  for (int r = 0; r < 4; r++) { m_run[r] = -1e30f; l_run[r] = 0.f; }
  const float sm_scale = 0.08838834764831845f;

  int kend = q0 + 64;
  for (int sk0 = 0; sk0 < kend; sk0 += 64) {
    __syncthreads();   // previous iter's Ks/Vs reads done
    for (int c = tid; c < 1024; c += 256) {
      int r = c >> 4, dp = (c & 15) * 8;
      *(int4*)&Ks[r][dp] = *(const int4*)&Kp[(size_t)(sk0 + r) * D_ + dp];
    }
    for (int c = tid; c < 1024; c += 256) {
      int d = c >> 3, sp = (c & 7) * 8;
      *(int4*)&Vs[d][sp] = *(const int4*)&Vp[(size_t)d * S_ + sk0 + sp];
    }
    __syncthreads();

    f32x4 st[4] = {};
    for (int nt = 0; nt < 4; nt++)
      for (int ks = 0; ks < 4; ks++) {
        bf16x8 bk = *(const bf16x8*)&Ks[nt * 16 + l15][ks * 32 + quad * 8];
        st[nt] = __builtin_amdgcn_mfma_f32_16x16x32_bf16(aq[ks], bk, st[nt], 0, 0, 0);
      }

    int qg = q0 + wid * 16 + quad * 4;
    float mnew[4], alpha[4];
    for (int r = 0; r < 4; r++) {
      float rmax = -1e30f;
      for (int nt = 0; nt < 4; nt++) {
        int kg = sk0 + nt * 16 + l15;
        float vsc = st[nt][r] * sm_scale;
        if (kg > qg + r) vsc = -1e30f;
        st[nt][r] = vsc;
        rmax = fmaxf(rmax, vsc);
      }
      for (int off = 1; off < 16; off <<= 1) rmax = fmaxf(rmax, __shfl_xor(rmax, off));
      mnew[r] = fmaxf(m_run[r], rmax);
      alpha[r] = __expf(m_run[r] - mnew[r]);
      float s_ = 0.f;
      for (int nt = 0; nt < 4; nt++) {
        float p = __expf(st[nt][r] - mnew[r]);
        st[nt][r] = p;
        s_ += p;
      }
      for (int off = 1; off < 16; off <<= 1) s_ += __shfl_xor(s_, off);
      l_run[r] = l_run[r] * alpha[r] + s_;
      m_run[r] = mnew[r];
    }

    for (int nt = 0; nt < 4; nt++)
      for (int r = 0; r < 4; r++)
        Ps[wid][quad * 4 + r][nt * 16 + l15] = (__bf16)st[nt][r];

    for (int dt = 0; dt < 8; dt++)
      for (int r = 0; r < 4; r++)
        o_acc[dt][r] *= alpha[r];

    __syncthreads();   // P visible; also keeps waves together

    for (int ks2 = 0; ks2 < 2; ks2++) {
      bf16x8 ap = *(const bf16x8*)&Ps[wid][l15][ks2 * 32 + quad * 8];
      for (int dt = 0; dt < 8; dt++) {
        bf16x8 bv = *(const bf16x8*)&Vs[dt * 16 + l15][ks2 * 32 + quad * 8];
        o_acc[dt] = __builtin_amdgcn_mfma_f32_16x16x32_bf16(ap, bv, o_acc[dt], 0, 0, 0);
      }
    }
  }

  size_t trow = (size_t)b * S_ + q0 + wid * 16 + quad * 4;
  for (int dt = 0; dt < 8; dt++) {
    int e = h * D_ + dt * 16 + l15;
    for (int r = 0; r < 4; r++) {
      float val = o_acc[dt][r] / l_run[r];
      attn[(trow + r) * E_ + e] = (__bf16)val;
    }
  }
}

// ---------------------------------------------------------------- launch
extern "C" void kernel_launch(void* const* d_in, const int* in_sizes, int n_in,
                              void* d_out, int out_size, void* d_ws, size_t ws_size,
                              hipStream_t stream) {
  const float* hs    = (const float*)d_in[0];
  const float* qkv_w = (const float*)d_in[1];
  const float* o_w   = (const float*)d_in[2];
  const float* cosb  = (const float*)d_in[3];
  const float* sinb  = (const float*)d_in[4];
  const int*   bt    = (const int*)d_in[7];

  float* out = (float*)d_out;
  float* kc  = out + (size_t)T_ * E_;
  float* vc  = kc + (size_t)B_ * NB_ * H_ * BS_ * D_;

  // ws layout (288 MB): [hsb/attn 32MB][wT 96MB][oT 32MB][q 32][k 32][v 32][vT 32]
  char* ws = (char*)d_ws;
  __bf16* hsb  = (__bf16*)ws;
  __bf16* wT   = (__bf16*)(ws + 33554432);
  __bf16* oT   = wT + (size_t)3 * E_ * E_;
  __bf16* qb   = (__bf16*)(ws + 167772160);
  __bf16* kb   = qb + (size_t)B_ * H_ * S_ * D_;
  __bf16* vb   = kb + (size_t)B_ * H_ * S_ * D_;
  __bf16* vTt  = (__bf16*)(ws + 268435456);
  __bf16* attn = hsb;  // hs no longer needed once attention runs

  k_convert_hs<<<dim3(T_ * E_ / 4 / 256), dim3(256), 0, stream>>>(hs, hsb, T_ * E_ / 4);
  k_transpose_w<<<dim3(128, 128, 3), dim3(256), 0, stream>>>(qkv_w, wT);
  k_transpose_w<<<dim3(128, 128, 1), dim3(256), 0, stream>>>(o_w, oT);
  k_gemm_qkv<<<dim3(768), dim3(512), 0, stream>>>(hsb, wT, qb);
  k_rope<<<dim3(32768), dim3(256), 0, stream>>>(qb, kb, vb, cosb, sinb, bt, kc, vc);
  k_transpose_v<<<dim3(32, 4, 128), dim3(256), 0, stream>>>(vb, vTt);
  k_attn<<<dim3(16, 32, 4), dim3(256), 0, stream>>>(qb, kb, vTt, attn);
  k_gemm_out<<<dim3(256), dim3(512), 0, stream>>>(attn, oT, out);
}